// Round 8
// baseline (144.062 us; speedup 1.0000x reference)
//
#include <hip/hip_runtime.h>
#include <hip/hip_bf16.h>

#define DI __device__ __forceinline__

typedef __attribute__((ext_vector_type(8))) __bf16 bf16x8;
typedef __attribute__((ext_vector_type(4))) float f32x4;
typedef __attribute__((ext_vector_type(8))) short short8;
typedef __attribute__((ext_vector_type(4))) short short4v;
typedef unsigned short u16;

static constexpr int BB = 4, SS = 2048, EE = 1024, AA = 1024;

DI float bf2f(u16 u) { unsigned v = ((unsigned)u) << 16; float f; __builtin_memcpy(&f, &v, 4); return f; }
DI u16 f2bf(float f) { __hip_bfloat16 h = __float2bfloat16(f); u16 u; __builtin_memcpy(&u, &h, 2); return u; }

DI void gload16(const void* g, void* l) {
  __builtin_amdgcn_global_load_lds((const __attribute__((address_space(1))) void*)g,
                                   (__attribute__((address_space(3))) void*)l, 16, 0, 0);
}

// bijective XCD swizzle: nwg % 8 == 0.
DI int xcd_swz(int lin, int nwg) {
  int cpx = nwg >> 3;
  return (lin & 7) * cpx + (lin >> 3);
}

// LDS tile rows are 128B (64 bf16). Physical 16B chunk = logical ^ (row&7).
DI bf16x8 read_frag(const char* lds, int R, int c) {
  return *(const bf16x8*)(lds + R * 128 + ((c ^ (R & 7)) << 4));
}

// ================= proj: 256x192 4-phase GEMM with deep pipeline =================
// C[8192][3072] = Xb @ Wt^T. 512 wgs = exactly 2 rounds. 8 waves (2M x 4N), wave 128x48.
// BK=64, 16 K-tiles. LDS 144KB: A TRIPLE-buffered (3x32KB, staged 2 tiles ahead),
// B DOUBLE-buffered (2x24KB, staged 1 ahead; B is L2-resident). Per-tile wait = vmcnt(4)
// (A(t+2)'s 4 loads stay in flight) -- never 0 until the tail.
__global__ __launch_bounds__(512, 2) void k_proj6(const u16* __restrict__ Xb, const u16* __restrict__ Wt,
                                                  u16* __restrict__ Qb, u16* __restrict__ Vt) {
  __shared__ __align__(16) char smem[147456];   // A: 3x32KB @0; B: 2x24KB @98304
  const int tid = threadIdx.x, lane = tid & 63, wid = tid >> 6;
  const int wr = wid >> 2, wc = wid & 3;        // 2M x 4N waves
  const int lane15 = lane & 15, lhi = lane >> 4;
  const int lin = blockIdx.x;                   // 512 wgs; lin&7 = XCD
  const int jj = lin >> 3;                      // [0,64) within XCD
  const int mt = (lin & 7) * 4 + (jj & 3);      // [0,32): 4 m-tiles per XCD
  const int nt = jj >> 2;                       // [0,16): m-fastest
  const u16* Ap = Xb + (size_t)mt * 256 * EE;
  const u16* Bp = Wt + (size_t)nt * 192 * EE;

  auto stageA = [&](int t, int buf) {           // 256x64: 32 blocks, 4 insts/wave
    char* dst = smem + buf * 32768;
#pragma unroll
    for (int i = 0; i < 4; ++i) {
      int blk = i * 8 + wid;
      int r = blk * 8 + (lane >> 3);
      int c = (lane & 7) ^ (r & 7);
      gload16((const char*)(Ap + (size_t)t * 64 + (size_t)r * EE) + c * 16, dst + blk * 1024);
    }
  };
  auto stageB = [&](int t, int buf) {           // 192x64: 24 blocks, 3 insts/wave
    char* dst = smem + 98304 + buf * 24576;
#pragma unroll
    for (int i = 0; i < 3; ++i) {
      int blk = i * 8 + wid;
      int r = blk * 8 + (lane >> 3);
      int c = (lane & 7) ^ (r & 7);
      gload16((const char*)(Bp + (size_t)t * 64 + (size_t)r * EE) + c * 16, dst + blk * 1024);
    }
  };

  f32x4 acc[8][3];
#pragma unroll
  for (int i = 0; i < 8; ++i)
#pragma unroll
    for (int j = 0; j < 3; ++j) acc[i][j] = (f32x4)0.f;

  // prologue: B0 (3 loads), A0 (4), A1 (4). Drain B0+A0, keep A1 in flight.
  stageB(0, 0); stageA(0, 0); stageA(1, 1);
  asm volatile("s_waitcnt vmcnt(4)" ::: "memory");
  __builtin_amdgcn_s_barrier();

  int ab = 0;                                   // A ring index for tile t
#pragma unroll 1
  for (int t = 0; t < 16; ++t) {
    const char* As = smem + ab * 32768;
    const char* Bs = smem + 98304 + (t & 1) * 24576;
    const int asb = (ab >= 1) ? ab - 1 : 2;     // (ab+2)%3: freed at end of t-1
    bf16x8 bfr[3][2];

#pragma unroll
    for (int q = 0; q < 4; ++q) {
      if (q == 0) {
#pragma unroll
        for (int ni = 0; ni < 3; ++ni)
#pragma unroll
          for (int ks = 0; ks < 2; ++ks)
            bfr[ni][ks] = read_frag(Bs, wc * 48 + ni * 16 + lane15, ks * 4 + lhi);
      }
      bf16x8 af[2][2];
#pragma unroll
      for (int m2 = 0; m2 < 2; ++m2)
#pragma unroll
        for (int ks = 0; ks < 2; ++ks)
          af[m2][ks] = read_frag(As, wr * 128 + (q * 2 + m2) * 16 + lane15, ks * 4 + lhi);
      // B(t+1) issued first (q0), A(t+2) second (q1) -> A's 4 loads are youngest.
      if (q == 0 && t + 1 < 16) stageB(t + 1, (t + 1) & 1);
      if (q == 1 && t + 2 < 16) stageA(t + 2, asb);
      __builtin_amdgcn_s_barrier();
      asm volatile("s_waitcnt lgkmcnt(0)" ::: "memory");
      __builtin_amdgcn_sched_barrier(0);
      __builtin_amdgcn_s_setprio(1);
#pragma unroll
      for (int m2 = 0; m2 < 2; ++m2)
#pragma unroll
        for (int ni = 0; ni < 3; ++ni)
#pragma unroll
          for (int ks = 0; ks < 2; ++ks)
            acc[q * 2 + m2][ni] =
                __builtin_amdgcn_mfma_f32_16x16x32_bf16(af[m2][ks], bfr[ni][ks], acc[q * 2 + m2][ni], 0, 0, 0);
      __builtin_amdgcn_s_setprio(0);
      __builtin_amdgcn_sched_barrier(0);
      if (q == 3) {
        // need B(t+1) + A(t+1) landed for next tile; A(t+2) (4 youngest) stays in flight
        if (t < 14) asm volatile("s_waitcnt vmcnt(4)" ::: "memory");
        else        asm volatile("s_waitcnt vmcnt(0)" ::: "memory");
      }
      __builtin_amdgcn_s_barrier();
    }
    ab = (ab >= 2) ? 0 : ab + 1;
  }

  // epilogue: C/D layout col=lane&15, row=(lane>>4)*4+reg. Cols [0,2048)=Q|K row-major;
  // cols [2048,3072) = V written TRANSPOSED to Vt.
  const int r0 = mt * 256 + wr * 128;
  const int c0 = nt * 192 + wc * 48;
#pragma unroll
  for (int mi = 0; mi < 8; ++mi) {
    const int grow = r0 + mi * 16 + lhi * 4;        // 4 consecutive s-rows
    const int b = grow >> 11, s = grow & 2047;
#pragma unroll
    for (int ni = 0; ni < 3; ++ni) {
      const int col = c0 + ni * 16 + lane15;
      if (col < 2048) {
        u16* base = Qb + (size_t)(col >> 10) * ((size_t)BB * SS * AA);
#pragma unroll
        for (int r = 0; r < 4; ++r)
          base[(size_t)(grow + r) * AA + (col & 1023)] = f2bf(acc[mi][ni][r]);
      } else {
        const int a = col - 2048;
        short4v o;
#pragma unroll
        for (int r = 0; r < 4; ++r) o[r] = (short)f2bf(acc[mi][ni][r]);
        *(short4v*)(Vt + (size_t)b * AA * SS + (size_t)a * SS + s) = o;
      }
    }
  }
}

// ================= 128x128 GEMM core (scores / pv): T3-min double-buffered =================
DI void stage_tile(const u16* g, int ld, char* lds, int wid, int lane) {
#pragma unroll
  for (int i = 0; i < 4; ++i) {
    int blk = i * 4 + wid;
    int r = blk * 8 + (lane >> 3);
    int c = (lane & 7) ^ (r & 7);
    gload16((const char*)(g + (size_t)r * ld) + c * 16, lds + blk * 1024);
  }
}

DI void gemm_tile(const u16* Ap, int lda, const u16* Bp, int ldb, int ksteps,
                  char* smem, f32x4 acc[4][4]) {
  const int tid = threadIdx.x, lane = tid & 63, wid = tid >> 6;
  const int wr = wid >> 1, wc = wid & 1;
  stage_tile(Ap, lda, smem, wid, lane);
  stage_tile(Bp, ldb, smem + 16384, wid, lane);
  asm volatile("s_waitcnt vmcnt(0)" ::: "memory");
  __syncthreads();
#pragma unroll 1
  for (int ks = 0; ks < ksteps; ++ks) {
    const char* As = smem + (ks & 1) * 32768;
    const char* Bs = As + 16384;
    char* nxt = smem + ((ks & 1) ^ 1) * 32768;
    if (ks + 1 < ksteps) {
      stage_tile(Ap + (size_t)(ks + 1) * 64, lda, nxt, wid, lane);
      stage_tile(Bp + (size_t)(ks + 1) * 64, ldb, nxt + 16384, wid, lane);
    }
#pragma unroll
    for (int ksub = 0; ksub < 2; ++ksub) {
      const int c = ksub * 4 + (lane >> 4);
      bf16x8 af[4], bfr[4];
#pragma unroll
      for (int mi = 0; mi < 4; ++mi) af[mi] = read_frag(As, wr * 64 + mi * 16 + (lane & 15), c);
#pragma unroll
      for (int ni = 0; ni < 4; ++ni) bfr[ni] = read_frag(Bs, wc * 64 + ni * 16 + (lane & 15), c);
#pragma unroll
      for (int mi = 0; mi < 4; ++mi)
#pragma unroll
        for (int ni = 0; ni < 4; ++ni)
          acc[mi][ni] = __builtin_amdgcn_mfma_f32_16x16x32_bf16(af[mi], bfr[ni], acc[mi][ni], 0, 0, 0);
    }
    if (ks + 1 < ksteps) asm volatile("s_waitcnt vmcnt(0)" ::: "memory");
    __syncthreads();
  }
}

// ---------- prep: cast X -> bf16, cast+transpose W -> Wt, zero rowsum ----------
__global__ __launch_bounds__(256) void k_prep(const float* __restrict__ X, const float* __restrict__ Wq,
                                              const float* __restrict__ Wk, const float* __restrict__ Wv,
                                              u16* __restrict__ Xb, u16* __restrict__ Wt,
                                              float* __restrict__ rowsum) {
  __shared__ float t[64][65];
  const int bid = blockIdx.x;
  if (bid < 8192) {
    if (bid < 32) rowsum[bid * 256 + threadIdx.x] = 0.f;
    size_t i = ((size_t)bid * 256 + threadIdx.x) * 4;
    f32x4 f = *(const f32x4*)(X + i);
    short4v o;
#pragma unroll
    for (int j = 0; j < 4; ++j) o[j] = (short)f2bf(f[j]);
    *(short4v*)(Xb + i) = o;
  } else {
    const int bx = bid - 8192;                 // [0,768)
    const int w = bx >> 8, rem = bx & 255;
    const int k0 = (rem & 15) * 64, n0 = (rem >> 4) * 64;
    const float* W = (w == 0) ? Wq : ((w == 1) ? Wk : Wv);
    u16* Wo = Wt + (size_t)w * EE * AA;
    const int tx = threadIdx.x & 63, ty = threadIdx.x >> 6;
#pragma unroll
    for (int r = 0; r < 16; ++r) {
      int k = r * 4 + ty;
      t[k][tx] = W[(size_t)(k0 + k) * AA + n0 + tx];
    }
    __syncthreads();
#pragma unroll
    for (int r = 0; r < 16; ++r) {
      int n = r * 4 + ty;
      Wo[(size_t)(n0 + n) * EE + k0 + tx] = f2bf(t[tx][n]);
    }
  }
}

// ---------- P = exp(Q @ K^T / 32) causal, + rowsum atomics ----------
__global__ __launch_bounds__(256) void k_scores(const u16* __restrict__ Q, const u16* __restrict__ K,
                                                u16* __restrict__ Sc, float* __restrict__ rowsum) {
  __shared__ __align__(16) char smem[65536];
  const int wg = xcd_swz(blockIdx.x, 544);
  const int b = wg / 136, t = wg % 136;
  int i = (int)((sqrtf(8.f * t + 1.f) - 1.f) * 0.5f);
  while ((i + 1) * (i + 2) / 2 <= t) ++i;
  while (i * (i + 1) / 2 > t) --i;
  const int j = t - i * (i + 1) / 2;
  const u16* Ap = Q + (size_t)b * SS * AA + (size_t)i * 128 * AA;
  const u16* Bp = K + (size_t)b * SS * AA + (size_t)j * 128 * AA;
  u16* Op = Sc + (size_t)b * SS * SS;
  float* rs = rowsum + (size_t)b * SS;
  f32x4 acc[4][4];
#pragma unroll
  for (int x = 0; x < 4; ++x)
#pragma unroll
    for (int y = 0; y < 4; ++y) acc[x][y] = (f32x4)0.f;
  gemm_tile(Ap, AA, Bp, AA, AA / 64, smem, acc);
  const int lane = threadIdx.x & 63, wid = threadIdx.x >> 6;
  const int r0 = i * 128 + (wid >> 1) * 64, c0 = j * 128 + (wid & 1) * 64;
#pragma unroll
  for (int mi = 0; mi < 4; ++mi)
#pragma unroll
    for (int r = 0; r < 4; ++r) {
      const int row = r0 + mi * 16 + ((lane >> 4) << 2) + r;
      float psum = 0.f;
#pragma unroll
      for (int ni = 0; ni < 4; ++ni) {
        const int col = c0 + ni * 16 + (lane & 15);
        float e = (col <= row) ? __expf(acc[mi][ni][r] * 0.03125f) : 0.f;
        psum += e;
        Op[(size_t)row * SS + col] = f2bf(e);
      }
      psum += __shfl_xor(psum, 1, 16);
      psum += __shfl_xor(psum, 2, 16);
      psum += __shfl_xor(psum, 4, 16);
      psum += __shfl_xor(psum, 8, 16);
      if ((lane & 15) == 0) atomicAdd(&rs[row], psum);
    }
}

// ---------- out = (P @ Vt^T) / rowsum (causal K-loop), fp32 out ----------
// Perfect XCD balance: XCD x handles i in {x, 15-x}.
__global__ __launch_bounds__(256) void k_pv(const u16* __restrict__ Sc, const u16* __restrict__ Vt,
                                            const float* __restrict__ rowsum, float* __restrict__ Out) {
  __shared__ __align__(16) char smem[65536];
  const int lin = blockIdx.x;          // 512; lin&7 = XCD
  const int x = lin & 7;
  const int j = lin >> 3;              // [0,64)
  const int b = j >> 4, half = (j >> 3) & 1, nt = j & 7;
  const int i = half ? (15 - x) : x;
  const u16* Ap = Sc + (size_t)b * SS * SS + (size_t)i * 128 * SS;
  const u16* Bp = Vt + (size_t)b * AA * SS + (size_t)nt * 128 * SS;
  const float* rs = rowsum + (size_t)b * SS;
  float* Op = Out + (size_t)b * SS * AA;
  f32x4 acc[4][4];
#pragma unroll
  for (int p = 0; p < 4; ++p)
#pragma unroll
    for (int q = 0; q < 4; ++q) acc[p][q] = (f32x4)0.f;
  gemm_tile(Ap, SS, Bp, SS, 2 * (i + 1), smem, acc);
  const int lane = threadIdx.x & 63, wid = threadIdx.x >> 6;
  const int r0 = i * 128 + (wid >> 1) * 64, c0 = nt * 128 + (wid & 1) * 64;
#pragma unroll
  for (int mi = 0; mi < 4; ++mi)
#pragma unroll
    for (int r = 0; r < 4; ++r) {
      const int row = r0 + mi * 16 + ((lane >> 4) << 2) + r;
      const float inv = 1.f / rs[row];
#pragma unroll
      for (int ni = 0; ni < 4; ++ni) {
        const int col = c0 + ni * 16 + (lane & 15);
        Op[(size_t)row * AA + col] = acc[mi][ni][r] * inv;
      }
    }
}

extern "C" void kernel_launch(void* const* d_in, const int* in_sizes, int n_in,
                              void* d_out, int out_size, void* d_ws, size_t ws_size,
                              hipStream_t stream) {
  const float* X  = (const float*)d_in[0];
  const float* Wq = (const float*)d_in[1];
  const float* Wk = (const float*)d_in[2];
  const float* Wv = (const float*)d_in[3];
  float* Out = (float*)d_out;
  char* ws = (char*)d_ws;
  u16* Xb = (u16*)ws;                              // 16 MiB: [8192][1024]
  u16* Wt = (u16*)(ws + (16u << 20));              // 6 MiB: [3072][1024] (n-major, Q|K|V)
  u16* Qb = (u16*)(ws + (22u << 20));              // 16 MiB  } Qb, Kb contiguous (16MiB apart)
  u16* Kb = (u16*)(ws + (38u << 20));              // 16 MiB  }
  u16* Vt = (u16*)(ws + (70u << 20));              // 16 MiB: per-batch [1024][2048]
  u16* Sc = (u16*)(ws + (86u << 20));              // 32 MiB: [4][2048][2048]
  float* rowsum = (float*)(ws + (118u << 20));     // 32 KiB: [4][2048]

  k_prep<<<dim3(8192 + 768), 256, 0, stream>>>(X, Wq, Wk, Wv, Xb, Wt, rowsum);
  k_proj6<<<dim3(512), 512, 0, stream>>>(Xb, Wt, Qb, Vt);
  k_scores<<<dim3(136 * BB), 256, 0, stream>>>(Qb, Kb, Sc, rowsum);
  k_pv<<<dim3(512), 256, 0, stream>>>(Sc, Vt, rowsum, Out);
}

// Round 9
// 142.677 us; speedup vs baseline: 1.0097x; 1.0097x over previous
//
#include <hip/hip_runtime.h>
#include <hip/hip_bf16.h>

#define DI __device__ __forceinline__

typedef __attribute__((ext_vector_type(8))) __bf16 bf16x8;
typedef __attribute__((ext_vector_type(4))) float f32x4;
typedef __attribute__((ext_vector_type(8))) short short8;
typedef __attribute__((ext_vector_type(4))) short short4v;
typedef unsigned short u16;

static constexpr int BB = 4, SS = 2048, EE = 1024, AA = 1024;

DI float bf2f(u16 u) { unsigned v = ((unsigned)u) << 16; float f; __builtin_memcpy(&f, &v, 4); return f; }
DI u16 f2bf(float f) { __hip_bfloat16 h = __float2bfloat16(f); u16 u; __builtin_memcpy(&u, &h, 2); return u; }

DI void gload16(const void* g, void* l) {
  __builtin_amdgcn_global_load_lds((const __attribute__((address_space(1))) void*)g,
                                   (__attribute__((address_space(3))) void*)l, 16, 0, 0);
}

// bijective XCD swizzle: nwg % 8 == 0.
DI int xcd_swz(int lin, int nwg) {
  int cpx = nwg >> 3;
  return (lin & 7) * cpx + (lin >> 3);
}

// LDS tile rows are 128B (64 bf16). Physical 16B chunk = logical ^ (row&7).
DI bf16x8 read_frag(const char* lds, int R, int c) {
  return *(const bf16x8*)(lds + R * 128 + ((c ^ (R & 7)) << 4));
}

// ================= proj: 256x192 2-phase GEMM, deep pipeline =================
// C[8192][3072] = Xb @ Wt^T. 512 wgs = exactly 2 rounds. 8 waves (2M x 4N), wave 128x48.
// BK=64, 16 K-tiles. LDS 144KB: A TRIPLE-buffered (3x32KB, staged 2 ahead), B DOUBLE-
// buffered (2x24KB, staged 1 ahead). 2 phases/K-tile (ks=0/1), each: 11 ds_read + 24 MFMA
// (12 MFMA per barrier-pair vs proj3's 8). Counted vmcnt(4) once per K-tile; 0 only at tail.
__global__ __launch_bounds__(512, 2) void k_proj7(const u16* __restrict__ Xb, const u16* __restrict__ Wt,
                                                  u16* __restrict__ Qb, u16* __restrict__ Vt) {
  __shared__ __align__(16) char smem[147456];   // A: 3x32KB @0; B: 2x24KB @98304
  const int tid = threadIdx.x, lane = tid & 63, wid = tid >> 6;
  const int wr = wid >> 2, wc = wid & 3;        // 2M x 4N waves
  const int lane15 = lane & 15, lhi = lane >> 4;
  const int lin = blockIdx.x;                   // 512 wgs; lin&7 = XCD
  const int jj = lin >> 3;                      // [0,64) within XCD
  const int mt = (lin & 7) * 4 + (jj & 3);      // [0,32): 4 m-tiles per XCD
  const int nt = jj >> 2;                       // [0,16): m-fastest
  const u16* Ap = Xb + (size_t)mt * 256 * EE;
  const u16* Bp = Wt + (size_t)nt * 192 * EE;

  auto stageA = [&](int t, int buf) {           // 256x64: 32 blocks, 4 insts/wave
    char* dst = smem + buf * 32768;
#pragma unroll
    for (int i = 0; i < 4; ++i) {
      int blk = i * 8 + wid;
      int r = blk * 8 + (lane >> 3);
      int c = (lane & 7) ^ (r & 7);
      gload16((const char*)(Ap + (size_t)t * 64 + (size_t)r * EE) + c * 16, dst + blk * 1024);
    }
  };
  auto stageB = [&](int t, int buf) {           // 192x64: 24 blocks, 3 insts/wave
    char* dst = smem + 98304 + buf * 24576;
#pragma unroll
    for (int i = 0; i < 3; ++i) {
      int blk = i * 8 + wid;
      int r = blk * 8 + (lane >> 3);
      int c = (lane & 7) ^ (r & 7);
      gload16((const char*)(Bp + (size_t)t * 64 + (size_t)r * EE) + c * 16, dst + blk * 1024);
    }
  };

  f32x4 acc[8][3];
#pragma unroll
  for (int i = 0; i < 8; ++i)
#pragma unroll
    for (int j = 0; j < 3; ++j) acc[i][j] = (f32x4)0.f;

  // prologue: B0 (3), A0 (4), A1 (4). Drain B0+A0 (7 oldest), keep A1 in flight.
  stageB(0, 0); stageA(0, 0); stageA(1, 1);
  asm volatile("s_waitcnt vmcnt(4)" ::: "memory");
  __builtin_amdgcn_s_barrier();

  int ab = 0;                                   // A ring index for tile t
#pragma unroll 1
  for (int t = 0; t < 16; ++t) {
    const char* As = smem + ab * 32768;
    const char* Bs = smem + 98304 + (t & 1) * 24576;
    const int asb = (ab >= 1) ? ab - 1 : 2;     // (ab+2)%3: tenant t-1, reads drained

    // ---------- phase A: ks = 0 ----------
    {
      bf16x8 af[8], bfr[3];
#pragma unroll
      for (int mi = 0; mi < 8; ++mi) af[mi] = read_frag(As, wr * 128 + mi * 16 + lane15, lhi);
#pragma unroll
      for (int ni = 0; ni < 3; ++ni) bfr[ni] = read_frag(Bs, wc * 48 + ni * 16 + lane15, lhi);
      if (t + 1 < 16) stageB(t + 1, (t + 1) & 1);
      __builtin_amdgcn_s_barrier();
      asm volatile("s_waitcnt lgkmcnt(0)" ::: "memory");
      __builtin_amdgcn_sched_barrier(0);
      __builtin_amdgcn_s_setprio(1);
#pragma unroll
      for (int mi = 0; mi < 8; ++mi)
#pragma unroll
        for (int ni = 0; ni < 3; ++ni)
          acc[mi][ni] = __builtin_amdgcn_mfma_f32_16x16x32_bf16(af[mi], bfr[ni], acc[mi][ni], 0, 0, 0);
      __builtin_amdgcn_s_setprio(0);
      __builtin_amdgcn_sched_barrier(0);
      __builtin_amdgcn_s_barrier();
    }
    // ---------- phase B: ks = 1 ----------
    {
      bf16x8 af[8], bfr[3];
#pragma unroll
      for (int mi = 0; mi < 8; ++mi) af[mi] = read_frag(As, wr * 128 + mi * 16 + lane15, 4 + lhi);
#pragma unroll
      for (int ni = 0; ni < 3; ++ni) bfr[ni] = read_frag(Bs, wc * 48 + ni * 16 + lane15, 4 + lhi);
      if (t + 2 < 16) stageA(t + 2, asb);
      // in flight: A(t+1)=4, B(t+1)=3, A(t+2)=4. Drain oldest 7, keep A(t+2).
      if (t < 14)      asm volatile("s_waitcnt vmcnt(4)" ::: "memory");
      else             asm volatile("s_waitcnt vmcnt(0)" ::: "memory");
      __builtin_amdgcn_s_barrier();
      asm volatile("s_waitcnt lgkmcnt(0)" ::: "memory");
      __builtin_amdgcn_sched_barrier(0);
      __builtin_amdgcn_s_setprio(1);
#pragma unroll
      for (int mi = 0; mi < 8; ++mi)
#pragma unroll
        for (int ni = 0; ni < 3; ++ni)
          acc[mi][ni] = __builtin_amdgcn_mfma_f32_16x16x32_bf16(af[mi], bfr[ni], acc[mi][ni], 0, 0, 0);
      __builtin_amdgcn_s_setprio(0);
      __builtin_amdgcn_sched_barrier(0);
      __builtin_amdgcn_s_barrier();
    }
    ab = (ab >= 2) ? 0 : ab + 1;
  }

  // epilogue: C/D layout col=lane&15, row=(lane>>4)*4+reg. Cols [0,2048)=Q|K row-major;
  // cols [2048,3072) = V written TRANSPOSED to Vt.
  const int r0 = mt * 256 + wr * 128;
  const int c0 = nt * 192 + wc * 48;
#pragma unroll
  for (int mi = 0; mi < 8; ++mi) {
    const int grow = r0 + mi * 16 + lhi * 4;        // 4 consecutive s-rows
    const int b = grow >> 11, s = grow & 2047;
#pragma unroll
    for (int ni = 0; ni < 3; ++ni) {
      const int col = c0 + ni * 16 + lane15;
      if (col < 2048) {
        u16* base = Qb + (size_t)(col >> 10) * ((size_t)BB * SS * AA);
#pragma unroll
        for (int r = 0; r < 4; ++r)
          base[(size_t)(grow + r) * AA + (col & 1023)] = f2bf(acc[mi][ni][r]);
      } else {
        const int a = col - 2048;
        short4v o;
#pragma unroll
        for (int r = 0; r < 4; ++r) o[r] = (short)f2bf(acc[mi][ni][r]);
        *(short4v*)(Vt + (size_t)b * AA * SS + (size_t)a * SS + s) = o;
      }
    }
  }
}

// ================= 128x128 GEMM core (scores / pv): T3-min double-buffered =================
DI void stage_tile(const u16* g, int ld, char* lds, int wid, int lane) {
#pragma unroll
  for (int i = 0; i < 4; ++i) {
    int blk = i * 4 + wid;
    int r = blk * 8 + (lane >> 3);
    int c = (lane & 7) ^ (r & 7);
    gload16((const char*)(g + (size_t)r * ld) + c * 16, lds + blk * 1024);
  }
}

DI void gemm_tile(const u16* Ap, int lda, const u16* Bp, int ldb, int ksteps,
                  char* smem, f32x4 acc[4][4]) {
  const int tid = threadIdx.x, lane = tid & 63, wid = tid >> 6;
  const int wr = wid >> 1, wc = wid & 1;
  stage_tile(Ap, lda, smem, wid, lane);
  stage_tile(Bp, ldb, smem + 16384, wid, lane);
  asm volatile("s_waitcnt vmcnt(0)" ::: "memory");
  __syncthreads();
#pragma unroll 1
  for (int ks = 0; ks < ksteps; ++ks) {
    const char* As = smem + (ks & 1) * 32768;
    const char* Bs = As + 16384;
    char* nxt = smem + ((ks & 1) ^ 1) * 32768;
    if (ks + 1 < ksteps) {
      stage_tile(Ap + (size_t)(ks + 1) * 64, lda, nxt, wid, lane);
      stage_tile(Bp + (size_t)(ks + 1) * 64, ldb, nxt + 16384, wid, lane);
    }
#pragma unroll
    for (int ksub = 0; ksub < 2; ++ksub) {
      const int c = ksub * 4 + (lane >> 4);
      bf16x8 af[4], bfr[4];
#pragma unroll
      for (int mi = 0; mi < 4; ++mi) af[mi] = read_frag(As, wr * 64 + mi * 16 + (lane & 15), c);
#pragma unroll
      for (int ni = 0; ni < 4; ++ni) bfr[ni] = read_frag(Bs, wc * 64 + ni * 16 + (lane & 15), c);
#pragma unroll
      for (int mi = 0; mi < 4; ++mi)
#pragma unroll
        for (int ni = 0; ni < 4; ++ni)
          acc[mi][ni] = __builtin_amdgcn_mfma_f32_16x16x32_bf16(af[mi], bfr[ni], acc[mi][ni], 0, 0, 0);
    }
    if (ks + 1 < ksteps) asm volatile("s_waitcnt vmcnt(0)" ::: "memory");
    __syncthreads();
  }
}

// ---------- prep: cast X -> bf16, cast+transpose W -> Wt, zero rowsum ----------
__global__ __launch_bounds__(256) void k_prep(const float* __restrict__ X, const float* __restrict__ Wq,
                                              const float* __restrict__ Wk, const float* __restrict__ Wv,
                                              u16* __restrict__ Xb, u16* __restrict__ Wt,
                                              float* __restrict__ rowsum) {
  __shared__ float t[64][65];
  const int bid = blockIdx.x;
  if (bid < 8192) {
    if (bid < 32) rowsum[bid * 256 + threadIdx.x] = 0.f;
    size_t i = ((size_t)bid * 256 + threadIdx.x) * 4;
    f32x4 f = *(const f32x4*)(X + i);
    short4v o;
#pragma unroll
    for (int j = 0; j < 4; ++j) o[j] = (short)f2bf(f[j]);
    *(short4v*)(Xb + i) = o;
  } else {
    const int bx = bid - 8192;                 // [0,768)
    const int w = bx >> 8, rem = bx & 255;
    const int k0 = (rem & 15) * 64, n0 = (rem >> 4) * 64;
    const float* W = (w == 0) ? Wq : ((w == 1) ? Wk : Wv);
    u16* Wo = Wt + (size_t)w * EE * AA;
    const int tx = threadIdx.x & 63, ty = threadIdx.x >> 6;
#pragma unroll
    for (int r = 0; r < 16; ++r) {
      int k = r * 4 + ty;
      t[k][tx] = W[(size_t)(k0 + k) * AA + n0 + tx];
    }
    __syncthreads();
#pragma unroll
    for (int r = 0; r < 16; ++r) {
      int n = r * 4 + ty;
      Wo[(size_t)(n0 + n) * EE + k0 + tx] = f2bf(t[tx][n]);
    }
  }
}

// ---------- P = exp(Q @ K^T / 32) causal, + rowsum atomics ----------
__global__ __launch_bounds__(256) void k_scores(const u16* __restrict__ Q, const u16* __restrict__ K,
                                                u16* __restrict__ Sc, float* __restrict__ rowsum) {
  __shared__ __align__(16) char smem[65536];
  const int wg = xcd_swz(blockIdx.x, 544);
  const int b = wg / 136, t = wg % 136;
  int i = (int)((sqrtf(8.f * t + 1.f) - 1.f) * 0.5f);
  while ((i + 1) * (i + 2) / 2 <= t) ++i;
  while (i * (i + 1) / 2 > t) --i;
  const int j = t - i * (i + 1) / 2;
  const u16* Ap = Q + (size_t)b * SS * AA + (size_t)i * 128 * AA;
  const u16* Bp = K + (size_t)b * SS * AA + (size_t)j * 128 * AA;
  u16* Op = Sc + (size_t)b * SS * SS;
  float* rs = rowsum + (size_t)b * SS;
  f32x4 acc[4][4];
#pragma unroll
  for (int x = 0; x < 4; ++x)
#pragma unroll
    for (int y = 0; y < 4; ++y) acc[x][y] = (f32x4)0.f;
  gemm_tile(Ap, AA, Bp, AA, AA / 64, smem, acc);
  const int lane = threadIdx.x & 63, wid = threadIdx.x >> 6;
  const int r0 = i * 128 + (wid >> 1) * 64, c0 = j * 128 + (wid & 1) * 64;
#pragma unroll
  for (int mi = 0; mi < 4; ++mi)
#pragma unroll
    for (int r = 0; r < 4; ++r) {
      const int row = r0 + mi * 16 + ((lane >> 4) << 2) + r;
      float psum = 0.f;
#pragma unroll
      for (int ni = 0; ni < 4; ++ni) {
        const int col = c0 + ni * 16 + (lane & 15);
        float e = (col <= row) ? __expf(acc[mi][ni][r] * 0.03125f) : 0.f;
        psum += e;
        Op[(size_t)row * SS + col] = f2bf(e);
      }
      psum += __shfl_xor(psum, 1, 16);
      psum += __shfl_xor(psum, 2, 16);
      psum += __shfl_xor(psum, 4, 16);
      psum += __shfl_xor(psum, 8, 16);
      if ((lane & 15) == 0) atomicAdd(&rs[row], psum);
    }
}

// ---------- out = (P @ Vt^T) / rowsum (causal K-loop), fp32 out ----------
// Perfect XCD balance: XCD x handles i in {x, 15-x}.
__global__ __launch_bounds__(256) void k_pv(const u16* __restrict__ Sc, const u16* __restrict__ Vt,
                                            const float* __restrict__ rowsum, float* __restrict__ Out) {
  __shared__ __align__(16) char smem[65536];
  const int lin = blockIdx.x;          // 512; lin&7 = XCD
  const int x = lin & 7;
  const int j = lin >> 3;              // [0,64)
  const int b = j >> 4, half = (j >> 3) & 1, nt = j & 7;
  const int i = half ? (15 - x) : x;
  const u16* Ap = Sc + (size_t)b * SS * SS + (size_t)i * 128 * SS;
  const u16* Bp = Vt + (size_t)b * AA * SS + (size_t)nt * 128 * SS;
  const float* rs = rowsum + (size_t)b * SS;
  float* Op = Out + (size_t)b * SS * AA;
  f32x4 acc[4][4];
#pragma unroll
  for (int p = 0; p < 4; ++p)
#pragma unroll
    for (int q = 0; q < 4; ++q) acc[p][q] = (f32x4)0.f;
  gemm_tile(Ap, SS, Bp, SS, 2 * (i + 1), smem, acc);
  const int lane = threadIdx.x & 63, wid = threadIdx.x >> 6;
  const int r0 = i * 128 + (wid >> 1) * 64, c0 = nt * 128 + (wid & 1) * 64;
#pragma unroll
  for (int mi = 0; mi < 4; ++mi)
#pragma unroll
    for (int r = 0; r < 4; ++r) {
      const int row = r0 + mi * 16 + ((lane >> 4) << 2) + r;
      const float inv = 1.f / rs[row];
#pragma unroll
      for (int ni = 0; ni < 4; ++ni) {
        const int col = c0 + ni * 16 + (lane & 15);
        Op[(size_t)row * AA + col] = acc[mi][ni][r] * inv;
      }
    }
}

extern "C" void kernel_launch(void* const* d_in, const int* in_sizes, int n_in,
                              void* d_out, int out_size, void* d_ws, size_t ws_size,
                              hipStream_t stream) {
  const float* X  = (const float*)d_in[0];
  const float* Wq = (const float*)d_in[1];
  const float* Wk = (const float*)d_in[2];
  const float* Wv = (const float*)d_in[3];
  float* Out = (float*)d_out;
  char* ws = (char*)d_ws;
  u16* Xb = (u16*)ws;                              // 16 MiB: [8192][1024]
  u16* Wt = (u16*)(ws + (16u << 20));              // 6 MiB: [3072][1024] (n-major, Q|K|V)
  u16* Qb = (u16*)(ws + (22u << 20));              // 16 MiB  } Qb, Kb contiguous (16MiB apart)
  u16* Kb = (u16*)(ws + (38u << 20));              // 16 MiB  }
  u16* Vt = (u16*)(ws + (70u << 20));              // 16 MiB: per-batch [1024][2048]
  u16* Sc = (u16*)(ws + (86u << 20));              // 32 MiB: [4][2048][2048]
  float* rowsum = (float*)(ws + (118u << 20));     // 32 KiB: [4][2048]

  k_prep<<<dim3(8192 + 768), 256, 0, stream>>>(X, Wq, Wk, Wv, Xb, Wt, rowsum);
  k_proj7<<<dim3(512), 512, 0, stream>>>(Xb, Wt, Qb, Vt);
  k_scores<<<dim3(136 * BB), 256, 0, stream>>>(Qb, Kb, Sc, rowsum);
  k_pv<<<dim3(512), 256, 0, stream>>>(Sc, Vt, rowsum, Out);
}

// Round 10
// 141.211 us; speedup vs baseline: 1.0202x; 1.0104x over previous
//
#include <hip/hip_runtime.h>
#include <hip/hip_bf16.h>

#define DI __device__ __forceinline__

typedef __attribute__((ext_vector_type(8))) __bf16 bf16x8;
typedef __attribute__((ext_vector_type(4))) float f32x4;
typedef __attribute__((ext_vector_type(8))) short short8;
typedef __attribute__((ext_vector_type(4))) short short4v;
typedef unsigned short u16;

static constexpr int BB = 4, SS = 2048, EE = 1024, AA = 1024;

DI float bf2f(u16 u) { unsigned v = ((unsigned)u) << 16; float f; __builtin_memcpy(&f, &v, 4); return f; }
DI u16 f2bf(float f) { __hip_bfloat16 h = __float2bfloat16(f); u16 u; __builtin_memcpy(&u, &h, 2); return u; }

DI void gload16(const void* g, void* l) {
  __builtin_amdgcn_global_load_lds((const __attribute__((address_space(1))) void*)g,
                                   (__attribute__((address_space(3))) void*)l, 16, 0, 0);
}

// bijective XCD swizzle: nwg % 8 == 0.
DI int xcd_swz(int lin, int nwg) {
  int cpx = nwg >> 3;
  return (lin & 7) * cpx + (lin >> 3);
}

// LDS tile rows are 128B (64 bf16). Physical 16B chunk = logical ^ (row&7).
DI bf16x8 read_frag(const char* lds, int R, int c) {
  return *(const bf16x8*)(lds + R * 128 + ((c ^ (R & 7)) << 4));
}

// ================= 128x128 GEMM core: T3-min double-buffered, 64KB -> 2 blocks/CU ==========
// Key lesson (r9): 2 blocks/CU co-residency (foreign waves fill barrier stalls) beats any
// 1-block/CU software pipeline tried in r3-r9 (755 TF ceiling there; this class ~900).
DI void stage_tile(const u16* g, int ld, char* lds, int wid, int lane) {
#pragma unroll
  for (int i = 0; i < 4; ++i) {
    int blk = i * 4 + wid;
    int r = blk * 8 + (lane >> 3);
    int c = (lane & 7) ^ (r & 7);
    gload16((const char*)(g + (size_t)r * ld) + c * 16, lds + blk * 1024);
  }
}

DI void gemm_tile(const u16* Ap, int lda, const u16* Bp, int ldb, int ksteps,
                  char* smem, f32x4 acc[4][4]) {
  const int tid = threadIdx.x, lane = tid & 63, wid = tid >> 6;
  const int wr = wid >> 1, wc = wid & 1;
  stage_tile(Ap, lda, smem, wid, lane);
  stage_tile(Bp, ldb, smem + 16384, wid, lane);
  asm volatile("s_waitcnt vmcnt(0)" ::: "memory");
  __syncthreads();
#pragma unroll 1
  for (int ks = 0; ks < ksteps; ++ks) {
    const char* As = smem + (ks & 1) * 32768;
    const char* Bs = As + 16384;
    char* nxt = smem + ((ks & 1) ^ 1) * 32768;
    if (ks + 1 < ksteps) {
      stage_tile(Ap + (size_t)(ks + 1) * 64, lda, nxt, wid, lane);
      stage_tile(Bp + (size_t)(ks + 1) * 64, ldb, nxt + 16384, wid, lane);
    }
#pragma unroll
    for (int ksub = 0; ksub < 2; ++ksub) {
      const int c = ksub * 4 + (lane >> 4);
      bf16x8 af[4], bfr[4];
#pragma unroll
      for (int mi = 0; mi < 4; ++mi) af[mi] = read_frag(As, wr * 64 + mi * 16 + (lane & 15), c);
#pragma unroll
      for (int ni = 0; ni < 4; ++ni) bfr[ni] = read_frag(Bs, wc * 64 + ni * 16 + (lane & 15), c);
#pragma unroll
      for (int mi = 0; mi < 4; ++mi)
#pragma unroll
        for (int ni = 0; ni < 4; ++ni)
          acc[mi][ni] = __builtin_amdgcn_mfma_f32_16x16x32_bf16(af[mi], bfr[ni], acc[mi][ni], 0, 0, 0);
    }
    if (ks + 1 < ksteps) asm volatile("s_waitcnt vmcnt(0)" ::: "memory");
    __syncthreads();
  }
}

// ================= proj: C[8192][3072] = Xb @ Wt^T via 128^2 tiles =================
// 1536 wgs = 3 exact rounds at 2 blocks/CU. Per-XCD: 8 m-tiles x (12+12 split) n-tiles,
// m-fastest -> L2 working set ~3.3MB < 4MB. Tile is wholly Q, K, or V; V written transposed.
__global__ __launch_bounds__(256) void k_proj8(const u16* __restrict__ Xb, const u16* __restrict__ Wt,
                                               u16* __restrict__ Qb, u16* __restrict__ Vt) {
  __shared__ __align__(16) char smem[65536];
  const int lin = blockIdx.x;            // 1536; lin&7 = XCD
  const int x = lin & 7;
  const int jj = lin >> 3;               // [0,192)
  const int nh = jj / 96, rem = jj - nh * 96;
  const int nt = nh * 12 + (rem >> 3);   // [0,24)
  const int mt = x * 8 + (rem & 7);      // [0,64): 8 m-tiles per XCD
  const u16* Ap = Xb + (size_t)mt * 128 * EE;
  const u16* Bp = Wt + (size_t)nt * 128 * EE;
  f32x4 acc[4][4];
#pragma unroll
  for (int p = 0; p < 4; ++p)
#pragma unroll
    for (int q = 0; q < 4; ++q) acc[p][q] = (f32x4)0.f;
  gemm_tile(Ap, EE, Bp, EE, EE / 64, smem, acc);

  const int lane = threadIdx.x & 63, wid = threadIdx.x >> 6;
  const int lane15 = lane & 15, lhi = lane >> 4;
  const int wr = wid >> 1, wc = wid & 1;
  const int r0 = mt * 128 + wr * 64;
  const int c0 = nt * 128 + wc * 64;
  if (nt < 16) {                         // Q (nt<8) or K (8<=nt<16), row-major
    u16* base = Qb + (size_t)(nt >> 3) * ((size_t)BB * SS * AA);
    const int cc = c0 & 1023;
#pragma unroll
    for (int mi = 0; mi < 4; ++mi)
#pragma unroll
      for (int ni = 0; ni < 4; ++ni)
#pragma unroll
        for (int r = 0; r < 4; ++r) {
          int row = r0 + mi * 16 + lhi * 4 + r;
          base[(size_t)row * AA + cc + ni * 16 + lane15] = f2bf(acc[mi][ni][r]);
        }
  } else {                               // V: write transposed to Vt[b][a][s]
#pragma unroll
    for (int mi = 0; mi < 4; ++mi) {
      const int grow = r0 + mi * 16 + lhi * 4;   // 4 consecutive s-rows
      const int b = grow >> 11, s = grow & 2047;
#pragma unroll
      for (int ni = 0; ni < 4; ++ni) {
        const int a = c0 - 2048 + ni * 16 + lane15;
        short4v o;
#pragma unroll
        for (int r = 0; r < 4; ++r) o[r] = (short)f2bf(acc[mi][ni][r]);
        *(short4v*)(Vt + (size_t)b * AA * SS + (size_t)a * SS + s) = o;
      }
    }
  }
}

// ---------- prep: cast X -> bf16, cast+transpose W -> Wt, zero rowsum ----------
__global__ __launch_bounds__(256) void k_prep(const float* __restrict__ X, const float* __restrict__ Wq,
                                              const float* __restrict__ Wk, const float* __restrict__ Wv,
                                              u16* __restrict__ Xb, u16* __restrict__ Wt,
                                              float* __restrict__ rowsum) {
  __shared__ float t[64][65];
  const int bid = blockIdx.x;
  if (bid < 8192) {
    if (bid < 32) rowsum[bid * 256 + threadIdx.x] = 0.f;
    size_t i = ((size_t)bid * 256 + threadIdx.x) * 4;
    f32x4 f = *(const f32x4*)(X + i);
    short4v o;
#pragma unroll
    for (int j = 0; j < 4; ++j) o[j] = (short)f2bf(f[j]);
    *(short4v*)(Xb + i) = o;
  } else {
    const int bx = bid - 8192;                 // [0,768)
    const int w = bx >> 8, rem = bx & 255;
    const int k0 = (rem & 15) * 64, n0 = (rem >> 4) * 64;
    const float* W = (w == 0) ? Wq : ((w == 1) ? Wk : Wv);
    u16* Wo = Wt + (size_t)w * EE * AA;
    const int tx = threadIdx.x & 63, ty = threadIdx.x >> 6;
#pragma unroll
    for (int r = 0; r < 16; ++r) {
      int k = r * 4 + ty;
      t[k][tx] = W[(size_t)(k0 + k) * AA + n0 + tx];
    }
    __syncthreads();
#pragma unroll
    for (int r = 0; r < 16; ++r) {
      int n = r * 4 + ty;
      Wo[(size_t)(n0 + n) * EE + k0 + tx] = f2bf(t[tx][n]);
    }
  }
}

// ---------- P = exp(Q @ K^T / 32) causal, + rowsum atomics ----------
__global__ __launch_bounds__(256) void k_scores(const u16* __restrict__ Q, const u16* __restrict__ K,
                                                u16* __restrict__ Sc, float* __restrict__ rowsum) {
  __shared__ __align__(16) char smem[65536];
  const int wg = xcd_swz(blockIdx.x, 544);
  const int b = wg / 136, t = wg % 136;
  int i = (int)((sqrtf(8.f * t + 1.f) - 1.f) * 0.5f);
  while ((i + 1) * (i + 2) / 2 <= t) ++i;
  while (i * (i + 1) / 2 > t) --i;
  const int j = t - i * (i + 1) / 2;
  const u16* Ap = Q + (size_t)b * SS * AA + (size_t)i * 128 * AA;
  const u16* Bp = K + (size_t)b * SS * AA + (size_t)j * 128 * AA;
  u16* Op = Sc + (size_t)b * SS * SS;
  float* rs = rowsum + (size_t)b * SS;
  f32x4 acc[4][4];
#pragma unroll
  for (int p = 0; p < 4; ++p)
#pragma unroll
    for (int q = 0; q < 4; ++q) acc[p][q] = (f32x4)0.f;
  gemm_tile(Ap, AA, Bp, AA, AA / 64, smem, acc);
  const int lane = threadIdx.x & 63, wid = threadIdx.x >> 6;
  const int r0 = i * 128 + (wid >> 1) * 64, c0 = j * 128 + (wid & 1) * 64;
#pragma unroll
  for (int mi = 0; mi < 4; ++mi)
#pragma unroll
    for (int r = 0; r < 4; ++r) {
      const int row = r0 + mi * 16 + ((lane >> 4) << 2) + r;
      float psum = 0.f;
#pragma unroll
      for (int ni = 0; ni < 4; ++ni) {
        const int col = c0 + ni * 16 + (lane & 15);
        float e = (col <= row) ? __expf(acc[mi][ni][r] * 0.03125f) : 0.f;
        psum += e;
        Op[(size_t)row * SS + col] = f2bf(e);
      }
      psum += __shfl_xor(psum, 1, 16);
      psum += __shfl_xor(psum, 2, 16);
      psum += __shfl_xor(psum, 4, 16);
      psum += __shfl_xor(psum, 8, 16);
      if ((lane & 15) == 0) atomicAdd(&rs[row], psum);
    }
}

// ---------- out = (P @ Vt^T) / rowsum (causal K-loop), fp32 out ----------
// Perfect XCD balance: XCD x handles i in {x, 15-x}.
__global__ __launch_bounds__(256) void k_pv(const u16* __restrict__ Sc, const u16* __restrict__ Vt,
                                            const float* __restrict__ rowsum, float* __restrict__ Out) {
  __shared__ __align__(16) char smem[65536];
  const int lin = blockIdx.x;          // 512; lin&7 = XCD
  const int x = lin & 7;
  const int j = lin >> 3;              // [0,64)
  const int b = j >> 4, half = (j >> 3) & 1, nt = j & 7;
  const int i = half ? (15 - x) : x;
  const u16* Ap = Sc + (size_t)b * SS * SS + (size_t)i * 128 * SS;
  const u16* Bp = Vt + (size_t)b * AA * SS + (size_t)nt * 128 * SS;
  const float* rs = rowsum + (size_t)b * SS;
  float* Op = Out + (size_t)b * SS * AA;
  f32x4 acc[4][4];
#pragma unroll
  for (int p = 0; p < 4; ++p)
#pragma unroll
    for (int q = 0; q < 4; ++q) acc[p][q] = (f32x4)0.f;
  gemm_tile(Ap, SS, Bp, SS, 2 * (i + 1), smem, acc);
  const int lane = threadIdx.x & 63, wid = threadIdx.x >> 6;
  const int r0 = i * 128 + (wid >> 1) * 64, c0 = nt * 128 + (wid & 1) * 64;
#pragma unroll
  for (int mi = 0; mi < 4; ++mi)
#pragma unroll
    for (int r = 0; r < 4; ++r) {
      const int row = r0 + mi * 16 + ((lane >> 4) << 2) + r;
      const float inv = 1.f / rs[row];
#pragma unroll
      for (int ni = 0; ni < 4; ++ni) {
        const int col = c0 + ni * 16 + (lane & 15);
        Op[(size_t)row * AA + col] = acc[mi][ni][r] * inv;
      }
    }
}

extern "C" void kernel_launch(void* const* d_in, const int* in_sizes, int n_in,
                              void* d_out, int out_size, void* d_ws, size_t ws_size,
                              hipStream_t stream) {
  const float* X  = (const float*)d_in[0];
  const float* Wq = (const float*)d_in[1];
  const float* Wk = (const float*)d_in[2];
  const float* Wv = (const float*)d_in[3];
  float* Out = (float*)d_out;
  char* ws = (char*)d_ws;
  u16* Xb = (u16*)ws;                              // 16 MiB: [8192][1024]
  u16* Wt = (u16*)(ws + (16u << 20));              // 6 MiB: [3072][1024] (n-major, Q|K|V)
  u16* Qb = (u16*)(ws + (22u << 20));              // 16 MiB  } Qb, Kb contiguous (16MiB apart)
  u16* Kb = (u16*)(ws + (38u << 20));              // 16 MiB  }
  u16* Vt = (u16*)(ws + (70u << 20));              // 16 MiB: per-batch [1024][2048]
  u16* Sc = (u16*)(ws + (86u << 20));              // 32 MiB: [4][2048][2048]
  float* rowsum = (float*)(ws + (118u << 20));     // 32 KiB: [4][2048]

  k_prep<<<dim3(8192 + 768), 256, 0, stream>>>(X, Wq, Wk, Wv, Xb, Wt, rowsum);
  k_proj8<<<dim3(1536), 256, 0, stream>>>(Xb, Wt, Qb, Vt);
  k_scores<<<dim3(136 * BB), 256, 0, stream>>>(Qb, Kb, Sc, rowsum);
  k_pv<<<dim3(512), 256, 0, stream>>>(Sc, Vt, rowsum, Out);
}

// Round 11
// 139.851 us; speedup vs baseline: 1.0301x; 1.0097x over previous
//
#include <hip/hip_runtime.h>
#include <hip/hip_bf16.h>

#define DI __device__ __forceinline__

typedef __attribute__((ext_vector_type(8))) __bf16 bf16x8;
typedef __attribute__((ext_vector_type(4))) float f32x4;
typedef __attribute__((ext_vector_type(8))) short short8;
typedef __attribute__((ext_vector_type(4))) short short4v;
typedef unsigned short u16;

static constexpr int BB = 4, SS = 2048, EE = 1024, AA = 1024;

DI float bf2f(u16 u) { unsigned v = ((unsigned)u) << 16; float f; __builtin_memcpy(&f, &v, 4); return f; }
DI u16 f2bf(float f) { __hip_bfloat16 h = __float2bfloat16(f); u16 u; __builtin_memcpy(&u, &h, 2); return u; }

DI void gload16(const void* g, void* l) {
  __builtin_amdgcn_global_load_lds((const __attribute__((address_space(1))) void*)g,
                                   (__attribute__((address_space(3))) void*)l, 16, 0, 0);
}

// bijective XCD swizzle: nwg % 8 == 0.
DI int xcd_swz(int lin, int nwg) {
  int cpx = nwg >> 3;
  return (lin & 7) * cpx + (lin >> 3);
}

// LDS tile rows are 128B (64 bf16). Physical 16B chunk = logical ^ (row&7).
DI bf16x8 read_frag(const char* lds, int R, int c) {
  return *(const bf16x8*)(lds + R * 128 + ((c ^ (R & 7)) << 4));
}

// ================= 128x128 GEMM core: T3-min double-buffered, 64KB -> 2 blocks/CU ==========
// Key lesson (r9/r10): 2 blocks/CU co-residency (foreign waves fill barrier stalls) beats
// every 1-block/CU software pipeline tried in r3-r9 (680-755 TF there; this class ~805+).
DI void stage_tile(const u16* g, int ld, char* lds, int wid, int lane) {
#pragma unroll
  for (int i = 0; i < 4; ++i) {
    int blk = i * 4 + wid;
    int r = blk * 8 + (lane >> 3);
    int c = (lane & 7) ^ (r & 7);
    gload16((const char*)(g + (size_t)r * ld) + c * 16, lds + blk * 1024);
  }
}

DI void gemm_tile(const u16* Ap, int lda, const u16* Bp, int ldb, int ksteps,
                  char* smem, f32x4 acc[4][4]) {
  const int tid = threadIdx.x, lane = tid & 63, wid = tid >> 6;
  const int wr = wid >> 1, wc = wid & 1;
  stage_tile(Ap, lda, smem, wid, lane);
  stage_tile(Bp, ldb, smem + 16384, wid, lane);
  asm volatile("s_waitcnt vmcnt(0)" ::: "memory");
  __syncthreads();
#pragma unroll 1
  for (int ks = 0; ks < ksteps; ++ks) {
    const char* As = smem + (ks & 1) * 32768;
    const char* Bs = As + 16384;
    char* nxt = smem + ((ks & 1) ^ 1) * 32768;
    if (ks + 1 < ksteps) {
      stage_tile(Ap + (size_t)(ks + 1) * 64, lda, nxt, wid, lane);
      stage_tile(Bp + (size_t)(ks + 1) * 64, ldb, nxt + 16384, wid, lane);
    }
#pragma unroll
    for (int ksub = 0; ksub < 2; ++ksub) {
      const int c = ksub * 4 + (lane >> 4);
      bf16x8 af[4], bfr[4];
#pragma unroll
      for (int mi = 0; mi < 4; ++mi) af[mi] = read_frag(As, wr * 64 + mi * 16 + (lane & 15), c);
#pragma unroll
      for (int ni = 0; ni < 4; ++ni) bfr[ni] = read_frag(Bs, wc * 64 + ni * 16 + (lane & 15), c);
#pragma unroll
      for (int mi = 0; mi < 4; ++mi)
#pragma unroll
        for (int ni = 0; ni < 4; ++ni)
          acc[mi][ni] = __builtin_amdgcn_mfma_f32_16x16x32_bf16(af[mi], bfr[ni], acc[mi][ni], 0, 0, 0);
    }
    if (ks + 1 < ksteps) asm volatile("s_waitcnt vmcnt(0)" ::: "memory");
    __syncthreads();
  }
}

// ================= proj: C[8192][3072] = Xb @ Wt^T via 128^2 tiles =================
// 1536 wgs = 3 exact rounds at 2 blocks/CU. Per-XCD: 8 m-tiles x (12+12 split) n-tiles,
// m-fastest -> L2 working set ~3.3MB < 4MB. Tile is wholly Q, K, or V; V written transposed.
__global__ __launch_bounds__(256) void k_proj8(const u16* __restrict__ Xb, const u16* __restrict__ Wt,
                                               u16* __restrict__ Qb, u16* __restrict__ Vt) {
  __shared__ __align__(16) char smem[65536];
  const int lin = blockIdx.x;            // 1536; lin&7 = XCD
  const int x = lin & 7;
  const int jj = lin >> 3;               // [0,192)
  const int nh = jj / 96, rem = jj - nh * 96;
  const int nt = nh * 12 + (rem >> 3);   // [0,24)
  const int mt = x * 8 + (rem & 7);      // [0,64): 8 m-tiles per XCD
  const u16* Ap = Xb + (size_t)mt * 128 * EE;
  const u16* Bp = Wt + (size_t)nt * 128 * EE;
  f32x4 acc[4][4];
#pragma unroll
  for (int p = 0; p < 4; ++p)
#pragma unroll
    for (int q = 0; q < 4; ++q) acc[p][q] = (f32x4)0.f;
  gemm_tile(Ap, EE, Bp, EE, EE / 64, smem, acc);

  const int lane = threadIdx.x & 63, wid = threadIdx.x >> 6;
  const int lane15 = lane & 15, lhi = lane >> 4;
  const int wr = wid >> 1, wc = wid & 1;
  const int r0 = mt * 128 + wr * 64;
  const int c0 = nt * 128 + wc * 64;
  if (nt < 16) {                         // Q (nt<8) or K (8<=nt<16), row-major
    u16* base = Qb + (size_t)(nt >> 3) * ((size_t)BB * SS * AA);
    const int cc = c0 & 1023;
#pragma unroll
    for (int mi = 0; mi < 4; ++mi)
#pragma unroll
      for (int ni = 0; ni < 4; ++ni)
#pragma unroll
        for (int r = 0; r < 4; ++r) {
          int row = r0 + mi * 16 + lhi * 4 + r;
          base[(size_t)row * AA + cc + ni * 16 + lane15] = f2bf(acc[mi][ni][r]);
        }
  } else {                               // V: write transposed to Vt[b][a][s]
#pragma unroll
    for (int mi = 0; mi < 4; ++mi) {
      const int grow = r0 + mi * 16 + lhi * 4;   // 4 consecutive s-rows
      const int b = grow >> 11, s = grow & 2047;
#pragma unroll
      for (int ni = 0; ni < 4; ++ni) {
        const int a = c0 - 2048 + ni * 16 + lane15;
        short4v o;
#pragma unroll
        for (int r = 0; r < 4; ++r) o[r] = (short)f2bf(acc[mi][ni][r]);
        *(short4v*)(Vt + (size_t)b * AA * SS + (size_t)a * SS + s) = o;
      }
    }
  }
}

// ---------- prep: cast X -> bf16, cast+transpose W -> Wt, zero rowsum ----------
__global__ __launch_bounds__(256) void k_prep(const float* __restrict__ X, const float* __restrict__ Wq,
                                              const float* __restrict__ Wk, const float* __restrict__ Wv,
                                              u16* __restrict__ Xb, u16* __restrict__ Wt,
                                              float* __restrict__ rowsum) {
  __shared__ float t[64][65];
  const int bid = blockIdx.x;
  if (bid < 8192) {
    if (bid < 32) rowsum[bid * 256 + threadIdx.x] = 0.f;
    size_t i = ((size_t)bid * 256 + threadIdx.x) * 4;
    f32x4 f = *(const f32x4*)(X + i);
    short4v o;
#pragma unroll
    for (int j = 0; j < 4; ++j) o[j] = (short)f2bf(f[j]);
    *(short4v*)(Xb + i) = o;
  } else {
    const int bx = bid - 8192;                 // [0,768)
    const int w = bx >> 8, rem = bx & 255;
    const int k0 = (rem & 15) * 64, n0 = (rem >> 4) * 64;
    const float* W = (w == 0) ? Wq : ((w == 1) ? Wk : Wv);
    u16* Wo = Wt + (size_t)w * EE * AA;
    const int tx = threadIdx.x & 63, ty = threadIdx.x >> 6;
#pragma unroll
    for (int r = 0; r < 16; ++r) {
      int k = r * 4 + ty;
      t[k][tx] = W[(size_t)(k0 + k) * AA + n0 + tx];
    }
    __syncthreads();
#pragma unroll
    for (int r = 0; r < 16; ++r) {
      int n = r * 4 + ty;
      Wo[(size_t)(n0 + n) * EE + k0 + tx] = f2bf(t[tx][n]);
    }
  }
}

// ---------- P = exp(Q @ K^T / 32) causal, + rowsum atomics ----------
__global__ __launch_bounds__(256) void k_scores(const u16* __restrict__ Q, const u16* __restrict__ K,
                                                u16* __restrict__ Sc, float* __restrict__ rowsum) {
  __shared__ __align__(16) char smem[65536];
  const int wg = xcd_swz(blockIdx.x, 544);
  const int b = wg / 136, t = wg % 136;
  int i = (int)((sqrtf(8.f * t + 1.f) - 1.f) * 0.5f);
  while ((i + 1) * (i + 2) / 2 <= t) ++i;
  while (i * (i + 1) / 2 > t) --i;
  const int j = t - i * (i + 1) / 2;
  const u16* Ap = Q + (size_t)b * SS * AA + (size_t)i * 128 * AA;
  const u16* Bp = K + (size_t)b * SS * AA + (size_t)j * 128 * AA;
  u16* Op = Sc + (size_t)b * SS * SS;
  float* rs = rowsum + (size_t)b * SS;
  f32x4 acc[4][4];
#pragma unroll
  for (int p = 0; p < 4; ++p)
#pragma unroll
    for (int q = 0; q < 4; ++q) acc[p][q] = (f32x4)0.f;
  gemm_tile(Ap, AA, Bp, AA, AA / 64, smem, acc);
  const int lane = threadIdx.x & 63, wid = threadIdx.x >> 6;
  const int r0 = i * 128 + (wid >> 1) * 64, c0 = j * 128 + (wid & 1) * 64;
#pragma unroll
  for (int mi = 0; mi < 4; ++mi)
#pragma unroll
    for (int r = 0; r < 4; ++r) {
      const int row = r0 + mi * 16 + ((lane >> 4) << 2) + r;
      float psum = 0.f;
#pragma unroll
      for (int ni = 0; ni < 4; ++ni) {
        const int col = c0 + ni * 16 + (lane & 15);
        float e = (col <= row) ? __expf(acc[mi][ni][r] * 0.03125f) : 0.f;
        psum += e;
        Op[(size_t)row * SS + col] = f2bf(e);
      }
      psum += __shfl_xor(psum, 1, 16);
      psum += __shfl_xor(psum, 2, 16);
      psum += __shfl_xor(psum, 4, 16);
      psum += __shfl_xor(psum, 8, 16);
      if ((lane & 15) == 0) atomicAdd(&rs[row], psum);
    }
}

// ---------- out = (P @ Vt^T) / rowsum (causal K-loop), fp32 out ----------
// Co-residency-aware pairing (r11): all 512 blocks resident at 2/CU; CU c hosts lin=c and
// lin=c+256. half=(lin>>8)&1 makes the pair {i=x, i=15-x}: every CU carries exactly 17
// K-tile units (was 2(x+1) or 2(16-x), up to 32), and the pair shares the same Vt panel.
__global__ __launch_bounds__(256) void k_pv(const u16* __restrict__ Sc, const u16* __restrict__ Vt,
                                            const float* __restrict__ rowsum, float* __restrict__ Out) {
  __shared__ __align__(16) char smem[65536];
  const int lin = blockIdx.x;          // 512; lin&7 = XCD
  const int x = lin & 7;
  const int half = (lin >> 8) & 1;     // co-resident partner has half^1
  const int rest = (lin >> 3) & 31;    // [0,32): b*8 + nt
  const int b = rest >> 3, nt = rest & 7;
  const int i = half ? (15 - x) : x;
  const u16* Ap = Sc + (size_t)b * SS * SS + (size_t)i * 128 * SS;
  const u16* Bp = Vt + (size_t)b * AA * SS + (size_t)nt * 128 * SS;
  const float* rs = rowsum + (size_t)b * SS;
  float* Op = Out + (size_t)b * SS * AA;
  f32x4 acc[4][4];
#pragma unroll
  for (int p = 0; p < 4; ++p)
#pragma unroll
    for (int q = 0; q < 4; ++q) acc[p][q] = (f32x4)0.f;
  gemm_tile(Ap, SS, Bp, SS, 2 * (i + 1), smem, acc);
  const int lane = threadIdx.x & 63, wid = threadIdx.x >> 6;
  const int r0 = i * 128 + (wid >> 1) * 64, c0 = nt * 128 + (wid & 1) * 64;
#pragma unroll
  for (int mi = 0; mi < 4; ++mi)
#pragma unroll
    for (int r = 0; r < 4; ++r) {
      const int row = r0 + mi * 16 + ((lane >> 4) << 2) + r;
      const float inv = 1.f / rs[row];
#pragma unroll
      for (int ni = 0; ni < 4; ++ni) {
        const int col = c0 + ni * 16 + (lane & 15);
        Op[(size_t)row * AA + col] = acc[mi][ni][r] * inv;
      }
    }
}

extern "C" void kernel_launch(void* const* d_in, const int* in_sizes, int n_in,
                              void* d_out, int out_size, void* d_ws, size_t ws_size,
                              hipStream_t stream) {
  const float* X  = (const float*)d_in[0];
  const float* Wq = (const float*)d_in[1];
  const float* Wk = (const float*)d_in[2];
  const float* Wv = (const float*)d_in[3];
  float* Out = (float*)d_out;
  char* ws = (char*)d_ws;
  u16* Xb = (u16*)ws;                              // 16 MiB: [8192][1024]
  u16* Wt = (u16*)(ws + (16u << 20));              // 6 MiB: [3072][1024] (n-major, Q|K|V)
  u16* Qb = (u16*)(ws + (22u << 20));              // 16 MiB  } Qb, Kb contiguous (16MiB apart)
  u16* Kb = (u16*)(ws + (38u << 20));              // 16 MiB  }
  u16* Vt = (u16*)(ws + (70u << 20));              // 16 MiB: per-batch [1024][2048]
  u16* Sc = (u16*)(ws + (86u << 20));              // 32 MiB: [4][2048][2048]
  float* rowsum = (float*)(ws + (118u << 20));     // 32 KiB: [4][2048]
  (void)Kb;

  k_prep<<<dim3(8192 + 768), 256, 0, stream>>>(X, Wq, Wk, Wv, Xb, Wt, rowsum);
  k_proj8<<<dim3(1536), 256, 0, stream>>>(Xb, Wt, Qb, Vt);
  k_scores<<<dim3(136 * BB), 256, 0, stream>>>(Qb, Kb, Sc, rowsum);
  k_pv<<<dim3(512), 256, 0, stream>>>(Sc, Vt, rowsum, Out);
}